// Round 18
// baseline (911.639 us; speedup 1.0000x reference)
//
#include <hip/hip_runtime.h>
#include <hip/hip_fp16.h>
#include <math.h>

#define NN 50000
#define EE 800000
#define DD 256
#define HH 256
#define LL 64
#define EP (EE + NN)          // edges + self loops
#define MP 50048              // 391 * 128, padded row count
#define NB2 ((NN + 255) / 256)
#define XLR 512               // fused xl|xr row stride (f16)

typedef __attribute__((ext_vector_type(8))) _Float16 half8;
typedef __attribute__((ext_vector_type(4))) float f32x4;

__device__ __forceinline__ float gelu_exact(float x) {
    return 0.5f * x * (1.f + erff(x * 0.70710678118654752f));
}
__device__ __forceinline__ ushort f2h(float x) {
    return __half_as_ushort(__float2half_rn(x));
}

// ================= f16 MFMA GEMM: A f16, B f16 (R17, measured-good) =======
// Tile 128x128, BK=32, EIGHT waves (512 thr) as 4M x 2N; per wave 2x4 frags.
// Double-buffered LDS, 1 barrier/K-step. Reg-prefetch 2 tiles ahead.
// 1D grid with bijective XCD swizzle (m204).
// OM=0: C float, scalar stores. OM=1: C __half via LDS-transposed epilogue.
template <int OM>
__global__ __launch_bounds__(512) void mm_f16(const ushort* __restrict__ A,
                                              const ushort* __restrict__ B,
                                              const float* __restrict__ bias,
                                              void* __restrict__ Cout,
                                              int M, int K, int Nc, int nbx) {
    __shared__ ushort As[2][128][40];
    __shared__ ushort Bs[2][128][40];
    const int nwg = gridDim.x;
    const int q = nwg >> 3, r = nwg & 7;
    const int xcd = blockIdx.x & 7, pos = blockIdx.x >> 3;
    const int swz = (xcd < r ? xcd * (q + 1) : r * (q + 1) + (xcd - r) * q) + pos;
    const int by = swz / nbx, bx = swz - by * nbx;
    const int row0 = by * 128;
    const int col0 = bx * 128;

    const int tid = threadIdx.x;
    const int lane = tid & 63;
    const int wid = tid >> 6;        // 0..7
    const int wr = wid >> 1;         // 0..3 (M quarter, 32 rows)
    const int wc = wid & 1;          // 0..1 (N half, 64 cols)
    const int srow = tid >> 2;       // 0..127
    const int sk = (tid & 3) << 3;   // 0,8,16,24
    const int fr = lane & 15;
    const int kg = (lane >> 4) << 3; // 0,8,16,24

    f32x4 acc[2][4] = {};
    int4 ra, rb;

    auto load_tile = [&](int k0) {
        ra = *(const int4*)(A + (size_t)(row0 + srow) * K + k0 + sk);
        int c = col0 + srow;
        int4 b4 = {0, 0, 0, 0};
        if (c < Nc) b4 = *(const int4*)(B + (size_t)c * K + k0 + sk);
        rb = b4;
    };

    // prologue: stage tile 0, prefetch tile 1 to regs
    load_tile(0);
    *(int4*)(&As[0][srow][sk]) = ra;
    *(int4*)(&Bs[0][srow][sk]) = rb;
    const int T = K >> 5;
    if (T > 1) load_tile(32);
    __syncthreads();

    for (int t = 0; t < T; t++) {
        const int cur = t & 1;
        half8 a[2], b[4];
#pragma unroll
        for (int m = 0; m < 2; m++)
            a[m] = *(const half8*)&As[cur][wr * 32 + m * 16 + fr][kg];
#pragma unroll
        for (int n = 0; n < 4; n++)
            b[n] = *(const half8*)&Bs[cur][wc * 64 + n * 16 + fr][kg];
#pragma unroll
        for (int m = 0; m < 2; m++)
#pragma unroll
            for (int n = 0; n < 4; n++)
                acc[m][n] = __builtin_amdgcn_mfma_f32_16x16x32_f16(a[m], b[n], acc[m][n], 0, 0, 0);
        if (t + 1 < T) {
            *(int4*)(&As[cur ^ 1][srow][sk]) = ra;
            *(int4*)(&Bs[cur ^ 1][srow][sk]) = rb;
            if (t + 2 < T) load_tile((t + 2) << 5);
            __syncthreads();
        }
    }

    if (OM == 1) {
        // ---- LDS-transposed epilogue (coalesced __half stores) ----
        __syncthreads();                         // all waves done with As/Bs
        ushort* tile = &As[0][0][0] + wid * 1024; // 16x64 f16 per wave (8KB tot)
        const int hi = lane >> 4;
        const int rrow = lane >> 3;              // 0..7
        const int c8 = (lane & 7) * 8;           // 0..56
#pragma unroll
        for (int m = 0; m < 2; m++) {
#pragma unroll
            for (int n = 0; n < 4; n++)
#pragma unroll
                for (int rr4 = 0; rr4 < 4; rr4++)
                    tile[(hi * 4 + rr4) * 64 + n * 16 + fr] = f2h(acc[m][n][rr4]);
#pragma unroll
            for (int r2 = 0; r2 < 2; r2++) {
                int row = r2 * 8 + rrow;
                uint4 vv = *(uint4*)&tile[row * 64 + c8];
                int grow = row0 + wr * 32 + m * 16 + row;
                if (grow < M)
                    *(uint4*)((__half*)Cout + (size_t)grow * Nc + col0 + wc * 64 + c8) = vv;
            }
        }
    } else {
        // C/D layout: col = lane&15, row = (lane>>4)*4 + r
#pragma unroll
        for (int m = 0; m < 2; m++) {
            int rbase = row0 + wr * 32 + m * 16 + (lane >> 4) * 4;
#pragma unroll
            for (int n = 0; n < 4; n++) {
                int c = col0 + wc * 64 + n * 16 + fr;
                if (c < Nc) {
                    float bv = bias ? bias[c] : 0.f;
#pragma unroll
                    for (int rr4 = 0; rr4 < 4; rr4++) {
                        int rr = rbase + rr4;
                        if (rr < M)
                            ((float*)Cout)[(size_t)rr * Nc + c] = acc[m][n][rr4] + bv;
                    }
                }
            }
        }
    }
}

// ================= weight transpose to f16 =================
struct WDesc { const float* W; ushort* T; int K; int N; };
struct WPack { WDesc d[19]; };

__global__ void wconv_kernel(WPack p) {
    WDesc w = p.d[blockIdx.y];
    int idx = blockIdx.x * 256 + threadIdx.x;
    int total = w.K * w.N;
    if (idx >= total) return;
    int n = idx / w.K, k = idx - n * w.K;
    w.T[idx] = f2h(w.W[(size_t)k * w.N + n]);
}

// ================= fp32 -> f16 conversion =================
__global__ void conv_kernel(const float* __restrict__ in, ushort* __restrict__ o,
                            int total4) {
    int i = blockIdx.x * 256 + threadIdx.x;
    if (i >= total4) return;
    float4 v = *(const float4*)(in + (size_t)i * 4);
    ushort4 h;
    h.x = f2h(v.x); h.y = f2h(v.y); h.z = f2h(v.z); h.w = f2h(v.w);
    *(ushort4*)(o + (size_t)i * 4) = h;
}

// ================= CSR build =================
__global__ void hist_kernel(const int* __restrict__ dst, int* __restrict__ deg) {
    int e = blockIdx.x * blockDim.x + threadIdx.x;
    if (e >= EP) return;
    int d = (e < EE) ? dst[e] : (e - EE);
    atomicAdd(&deg[d], 1);
}

__global__ void bsum_kernel(const int* __restrict__ deg, int* __restrict__ bsum) {
    __shared__ int wsum[4];
    int i = blockIdx.x * 256 + threadIdx.x;
    int v = (i < NN) ? deg[i] : 0;
#pragma unroll
    for (int off = 32; off; off >>= 1) v += __shfl_xor(v, off);
    if ((threadIdx.x & 63) == 0) wsum[threadIdx.x >> 6] = v;
    __syncthreads();
    if (threadIdx.x == 0) bsum[blockIdx.x] = wsum[0] + wsum[1] + wsum[2] + wsum[3];
}

__global__ void bscan_kernel(const int* __restrict__ bsum, int* __restrict__ boff,
                             int* __restrict__ row_last, int nb) {
    int lane = threadIdx.x;  // 64 threads, 1 block
    int carry = 0;
    for (int base = 0; base < nb; base += 64) {
        int i = base + lane;
        int v = (i < nb) ? bsum[i] : 0;
        int x = v;
#pragma unroll
        for (int off = 1; off < 64; off <<= 1) {
            int y = __shfl_up(x, off);
            if (lane >= off) x += y;
        }
        if (i < nb) boff[i] = carry + x - v;
        carry += __shfl(x, 63);
    }
    if (lane == 0) *row_last = carry;
}

__global__ void blockscan_kernel(const int* __restrict__ deg, const int* __restrict__ boff,
                                 int* __restrict__ row_ptr, int* __restrict__ wptr) {
    __shared__ int wsum[4];
    int i = blockIdx.x * 256 + threadIdx.x;
    int v = (i < NN) ? deg[i] : 0;
    int lane = threadIdx.x & 63, w = threadIdx.x >> 6;
    int x = v;
#pragma unroll
    for (int off = 1; off < 64; off <<= 1) {
        int y = __shfl_up(x, off);
        if (lane >= off) x += y;
    }
    if (lane == 63) wsum[w] = x;
    __syncthreads();
    int wo = 0;
    for (int j = 0; j < w; j++) wo += wsum[j];
    if (i < NN) {
        int excl = boff[blockIdx.x] + wo + x - v;
        row_ptr[i] = excl;
        wptr[i] = excl;
    }
}

__global__ void scatter_kernel(const int* __restrict__ src, const int* __restrict__ dst,
                               int* __restrict__ wptr, int* __restrict__ col) {
    int e = blockIdx.x * blockDim.x + threadIdx.x;
    if (e >= EP) return;
    int s, d;
    if (e < EE) { s = src[e]; d = dst[e]; } else { s = d = e - EE; }
    int pos = atomicAdd(&wptr[d], 1);
    col[pos] = s;
}

// ================= fused GATv2 edge phase =================
// R14 structure + 2-DEEP gather prefetch: xlr rows live mostly in L3
// (~600cy); 1-deep prefetch only covered ~250cy chain -> per-iter stall.
// Three row buffers (xc, x1, x2) rotate; load for t+2 issued at t.
__global__ __launch_bounds__(256) void gat_fused(const __half* __restrict__ xlr,
                                                 const int* __restrict__ row_ptr,
                                                 const int* __restrict__ col,
                                                 const float* __restrict__ att,
                                                 const float* __restrict__ bias,
                                                 ushort* __restrict__ out) {
    int wid = blockIdx.x * 4 + (threadIdx.x >> 6);
    if (wid >= NN) return;
    const int lane = threadIdx.x & 63;
    const int g = lane >> 4, sl = lane & 15;
    const int start = row_ptr[wid], end = row_ptr[wid + 1];

    union U8 { uint4 q[2]; __half2 h[8]; unsigned u[8]; };

    // xr slice (this node), elems sl*16 .. sl*16+15
    U8 xr;
    {
        const uint4* xrp = (const uint4*)(xlr + (size_t)wid * XLR + 256 + sl * 16);
        xr.q[0] = xrp[0]; xr.q[1] = xrp[1];
    }
    // att slice as packed f16
    U8 at;
    {
        const float4* ap = (const float4*)(att + sl * 16);
        float4 a0 = ap[0], a1 = ap[1], a2_ = ap[2], a3 = ap[3];
        at.h[0] = __floats2half2_rn(a0.x, a0.y); at.h[1] = __floats2half2_rn(a0.z, a0.w);
        at.h[2] = __floats2half2_rn(a1.x, a1.y); at.h[3] = __floats2half2_rn(a1.z, a1.w);
        at.h[4] = __floats2half2_rn(a2_.x, a2_.y); at.h[5] = __floats2half2_rn(a2_.z, a2_.w);
        at.h[6] = __floats2half2_rn(a3.x, a3.y); at.h[7] = __floats2half2_rn(a3.z, a3.w);
    }
    const __half2 c02 = __floats2half2_rn(0.2f, 0.2f);

    float m = -1e30f, ssum = 0.f;
    __half2 a2[8];
#pragma unroll
    for (int j = 0; j < 8; j++) a2[j] = __floats2half2_rn(0.f, 0.f);

    // prologue: load edge rows for t=0 and t=1
    int eg0 = start + g;
    bool vc = eg0 < end;
    int sc = col[vc ? eg0 : (end - 1)];
    U8 xc;
    {
        const uint4* xp = (const uint4*)(xlr + (size_t)sc * XLR + sl * 16);
        xc.q[0] = xp[0]; xc.q[1] = xp[1];
    }
    int eg1 = start + 4 + g;
    bool v1 = eg1 < end;
    int s1 = col[v1 ? eg1 : (end - 1)];
    U8 x1;
    {
        const uint4* xp = (const uint4*)(xlr + (size_t)s1 * XLR + sl * 16);
        x1.q[0] = xp[0]; x1.q[1] = xp[1];
    }

    for (int e0 = start; e0 < end; e0 += 4) {
        // ---- prefetch row for t+2 (2-deep: covers L3 latency) ----
        int eg2 = e0 + 8 + g;
        bool v2 = eg2 < end;
        int s2 = col[v2 ? eg2 : (end - 1)];
        U8 x2;
        {
            const uint4* xp = (const uint4*)(xlr + (size_t)s2 * XLR + sl * 16);
            x2.q[0] = xp[0]; x2.q[1] = xp[1];
        }

        // ---- score: dot(att, lrelu(xc + xr)), lrelu = max(x, 0.2x) ----
        float pf = 0.f;
#pragma unroll
        for (int i = 0; i < 8; i++) {
            union { __half2 h; unsigned u; } s2u, s02, l2;
            s2u.h = __hadd2(xc.h[i], xr.h[i]);
            s02.h = __hmul2(s2u.h, c02);
            asm("v_pk_max_f16 %0, %1, %2" : "=v"(l2.u) : "v"(s2u.u), "v"(s02.u));
            pf = __builtin_amdgcn_fdot2(l2.h, at.h[i], pf, false);
        }
#pragma unroll
        for (int off = 1; off < 16; off <<= 1) pf += __shfl_xor(pf, off);
        pf = vc ? pf : -INFINITY;

        // ---- branch-free online softmax, SINGLE exp ----
        float d = pf - m;
        float e1 = __expf(-fabsf(d));
        bool le = d <= 0.f;
        float f = le ? 1.f : e1;
        float w = le ? e1 : 1.f;
        ssum = fmaf(ssum, f, w);
        m = fmaxf(m, pf);
        __half2 f2 = __float2half2_rn(f);
        __half2 w2 = __float2half2_rn(w);
#pragma unroll
        for (int j = 0; j < 8; j++) a2[j] = __hfma2(a2[j], f2, __hmul2(xc.h[j], w2));

        // rotate pipeline
        xc = x1; vc = v1;
        x1 = x2; v1 = v2;
    }

    // ---- merge m/ssum across the 4 groups ----
    float m_all = m;
#pragma unroll
    for (int off = 16; off <= 32; off <<= 1) m_all = fmaxf(m_all, __shfl_xor(m_all, off));
    float fg = __expf(m - m_all);   // per-group rescale (0 for empty groups)
    ssum *= fg;
#pragma unroll
    for (int off = 16; off <= 32; off <<= 1) ssum += __shfl_xor(ssum, off);

    // ---- acc to f32, scale by fg ----
    float acc[16];
#pragma unroll
    for (int j = 0; j < 8; j++) {
        float2 fv = __half22float2(a2[j]);
        acc[2 * j] = fv.x * fg;
        acc[2 * j + 1] = fv.y * fg;
    }

    // ---- reduce-scatter across groups: lane ends with acc[4g + jj] summed ----
    const int gb1 = g >> 1, gb0 = g & 1;
    float t8[8];
#pragma unroll
    for (int jj = 0; jj < 8; jj++) {
        float keep = gb1 ? acc[8 + jj] : acc[jj];
        float send = gb1 ? acc[jj] : acc[8 + jj];
        t8[jj] = keep + __shfl_xor(send, 32);
    }
    float t4[4];
#pragma unroll
    for (int jj = 0; jj < 4; jj++) {
        float keep = gb0 ? t8[4 + jj] : t8[jj];
        float send = gb0 ? t8[jj] : t8[4 + jj];
        t4[jj] = keep + __shfl_xor(send, 16);
    }

    // ---- epilogue: lane (g,sl) handles elems sl*16 + 4g .. +3 ----
    float inv = 1.f / ssum;
    float4 b4 = *(const float4*)(bias + sl * 16 + 4 * g);
    const float* bf = (const float*)&b4;
    ushort4 hh;
    {
        ushort* hu = (ushort*)&hh;
#pragma unroll
        for (int jj = 0; jj < 4; jj++) {
            float o = gelu_exact(fmaf(t4[jj], inv, bf[jj]));
            hu[jj] = f2h(o);
        }
    }
    size_t ob = (size_t)wid * HH + sl * 16 + 4 * g;
    *(ushort4*)(out + ob) = hh;
}

// ================= mu/logstd/z + f16 of z =================
__global__ void z_kernel(const float* __restrict__ muls,
                         const float* __restrict__ mu_b, const float* __restrict__ ls_b,
                         const float* __restrict__ eps,
                         float* __restrict__ mu, float* __restrict__ lstd,
                         float* __restrict__ z, ushort* __restrict__ zf) {
    int i = blockIdx.x * 256 + threadIdx.x;
    if (i >= NN * LL) return;
    int row = i >> 6, j = i & 63;
    float mv = muls[(size_t)row * 128 + j] + mu_b[j];
    float lv = fminf(muls[(size_t)row * 128 + 64 + j] + ls_b[j], 10.f);
    float zv = fmaf(eps[i], __expf(lv), mv);
    mu[i] = mv;
    lstd[i] = lv;
    z[i] = zv;
    zf[i] = f2h(zv);
}

extern "C" void kernel_launch(void* const* d_in, const int* in_sizes, int n_in,
                              void* d_out, int out_size, void* d_ws, size_t ws_size,
                              hipStream_t stream) {
    const float* x       = (const float*)d_in[0];
    const int*   ei      = (const int*)d_in[1];
    const float* eps     = (const float*)d_in[2];
    const float* enc_Wl  = (const float*)d_in[3];
    const float* enc_Wr  = (const float*)d_in[4];
    const float* enc_att = (const float*)d_in[5];
    const float* enc_b   = (const float*)d_in[6];
    const float* mu_W    = (const float*)d_in[7];
    const float* mu_b    = (const float*)d_in[8];
    const float* ls_W    = (const float*)d_in[9];
    const float* ls_b    = (const float*)d_in[10];
    const float* dec0_Wl = (const float*)d_in[11];
    const float* dec0_Wr = (const float*)d_in[12];
    const float* dec0_att= (const float*)d_in[13];
    const float* dec0_b  = (const float*)d_in[14];
    const float* dec_Wl  = (const float*)d_in[15];
    const float* dec_Wr  = (const float*)d_in[16];
    const float* dec_att = (const float*)d_in[17];
    const float* dec_b   = (const float*)d_in[18];
    const float* out_W   = (const float*)d_in[19];
    const float* out_b   = (const float*)d_in[20];

    const int* esrc = ei;
    const int* edst = ei + EE;

    float* out_f = (float*)d_out;
    float* xrec = out_f;
    float* z    = out_f + (size_t)NN * DD;
    float* mu   = z + (size_t)NN * LL;
    float* lstd = mu + (size_t)NN * LL;

    // ---- workspace layout ----
    float* wsf = (float*)d_ws;
    __half* xlr = (__half*)wsf;                     // MP*512 f16  (= MP*256 floats)
    float* muls = wsf + (size_t)MP * 256;           // MP*128 f32
    ushort* Af = (ushort*)(muls + (size_t)MP * 128);// MP*256 f16 (GEMM A / gat out)
    ushort* Th = Af + (size_t)MP * 256;             // 1,048,576 f16
    int* deg     = (int*)(Th + 1048576);
    int* row_ptr = deg + NN;
    int* wptr    = row_ptr + NN + 1;
    int* col     = wptr + NN;
    int* bsum    = col + EP;
    int* boff    = bsum + 256;

    // weight pack: per-layer Wl/Wr pairs CONTIGUOUS so fused Nc=512 GEMM works
    WPack p;
    size_t off = 0;
    int wi = 0;
    auto add = [&](const float* W, int K, int N) {
        p.d[wi] = {W, Th + off, K, N};
        off += (size_t)K * N;
        wi++;
    };
    for (int l = 0; l < 4; l++) {                     // 0..7: enc (Wl,Wr)*4
        add(enc_Wl + (size_t)l * DD * HH, DD, HH);
        add(enc_Wr + (size_t)l * DD * HH, DD, HH);
    }
    add(dec0_Wl, LL, HH);                             // 8,9
    add(dec0_Wr, LL, HH);
    for (int l = 0; l < 3; l++) {                     // 10..15: dec (Wl,Wr)*3
        add(dec_Wl + (size_t)l * HH * HH, HH, HH);
        add(dec_Wr + (size_t)l * HH * HH, HH, HH);
    }
    add(out_W, HH, DD);                               // 16
    add(mu_W, HH, LL);                                // 17,18 contiguous -> Nc=128
    add(ls_W, HH, LL);

    const int eb = (EP + 255) / 256;
    const int nb = (NN + 3) / 4;            // gat: 4 nodes (waves) per block
    const int cb = (NN * 64 + 255) / 256;
    const int NBY = MP / 128;               // 391
    const int g_pair = 4 * NBY;             // Nc=512 fused Wl|Wr
    const int g_out  = 2 * NBY;             // Nc=256
    const int g_muls = 1 * NBY;             // Nc=128 fused mu|ls

    // ---- weight conversion + CSR build ----
    wconv_kernel<<<dim3(256, 19), 256, 0, stream>>>(p);
    (void)hipMemsetAsync(deg, 0, (size_t)NN * sizeof(int), stream);
    hist_kernel<<<eb, 256, 0, stream>>>(edst, deg);
    bsum_kernel<<<NB2, 256, 0, stream>>>(deg, bsum);
    bscan_kernel<<<1, 64, 0, stream>>>(bsum, boff, row_ptr + NN, NB2);
    blockscan_kernel<<<NB2, 256, 0, stream>>>(deg, boff, row_ptr, wptr);
    scatter_kernel<<<eb, 256, 0, stream>>>(esrc, edst, wptr, col);

    // ---- x -> f16 ----
    conv_kernel<<<cb, 256, 0, stream>>>(x, Af, NN * 64);

    // ---- encoder ----
    for (int l = 0; l < 4; l++) {
        mm_f16<1><<<g_pair, 512, 0, stream>>>(Af, p.d[2 * l].T, nullptr,
                                              xlr, NN, DD, XLR, 4);
        gat_fused<<<nb, 256, 0, stream>>>(xlr, row_ptr, col,
                                          enc_att + (size_t)l * HH,
                                          enc_b + (size_t)l * HH, Af);
    }

    // ---- mu / logstd / z (fused Nc=128 GEMM) ----
    mm_f16<0><<<g_muls, 512, 0, stream>>>(Af, p.d[17].T, nullptr,
                                          muls, NN, HH, 128, 1);
    z_kernel<<<(NN * LL + 255) / 256, 256, 0, stream>>>(muls, mu_b, ls_b, eps,
                                                        mu, lstd, z, Af);

    // ---- decoder ----
    for (int l = 0; l < 4; l++) {
        const ushort* BT;
        const float *at, *bb;
        int K;
        if (l == 0) {
            BT = p.d[8].T;                   // dec0 Wl|Wr combined [512][64]
            at = dec0_att; bb = dec0_b; K = LL;
        } else {
            BT = p.d[10 + 2 * (l - 1)].T;
            at = dec_att + (size_t)(l - 1) * HH;
            bb = dec_b + (size_t)(l - 1) * HH;
            K = HH;
        }
        mm_f16<1><<<g_pair, 512, 0, stream>>>(Af, BT, nullptr, xlr, NN, K, XLR, 4);
        gat_fused<<<nb, 256, 0, stream>>>(xlr, row_ptr, col, at, bb, Af);
    }

    // ---- output projection ----
    mm_f16<0><<<g_out, 512, 0, stream>>>(Af, p.d[16].T, out_b, xrec, NN, HH, DD, 2);
}

// Round 19
// 899.241 us; speedup vs baseline: 1.0138x; 1.0138x over previous
//
#include <hip/hip_runtime.h>
#include <hip/hip_fp16.h>
#include <math.h>

#define NN 50000
#define EE 800000
#define DD 256
#define HH 256
#define LL 64
#define EP (EE + NN)          // edges + self loops
#define MP 50048              // 391 * 128, padded row count
#define NB2 ((NN + 255) / 256)
#define XLR 512               // fused xl|xr row stride (f16)

typedef __attribute__((ext_vector_type(8))) _Float16 half8;
typedef __attribute__((ext_vector_type(4))) float f32x4;

__device__ __forceinline__ float gelu_exact(float x) {
    return 0.5f * x * (1.f + erff(x * 0.70710678118654752f));
}
__device__ __forceinline__ ushort f2h(float x) {
    return __half_as_ushort(__float2half_rn(x));
}

// ================= f16 MFMA GEMM: A f16, B f16 (R17, measured-good) =======
// Tile 128x128, BK=32, EIGHT waves (512 thr) as 4M x 2N; per wave 2x4 frags.
// Double-buffered LDS, 1 barrier/K-step. Reg-prefetch 2 tiles ahead.
// 1D grid with bijective XCD swizzle (m204).
// OM=0: C float, scalar stores. OM=1: C __half via LDS-transposed epilogue.
template <int OM>
__global__ __launch_bounds__(512) void mm_f16(const ushort* __restrict__ A,
                                              const ushort* __restrict__ B,
                                              const float* __restrict__ bias,
                                              void* __restrict__ Cout,
                                              int M, int K, int Nc, int nbx) {
    __shared__ ushort As[2][128][40];
    __shared__ ushort Bs[2][128][40];
    const int nwg = gridDim.x;
    const int q = nwg >> 3, r = nwg & 7;
    const int xcd = blockIdx.x & 7, pos = blockIdx.x >> 3;
    const int swz = (xcd < r ? xcd * (q + 1) : r * (q + 1) + (xcd - r) * q) + pos;
    const int by = swz / nbx, bx = swz - by * nbx;
    const int row0 = by * 128;
    const int col0 = bx * 128;

    const int tid = threadIdx.x;
    const int lane = tid & 63;
    const int wid = tid >> 6;        // 0..7
    const int wr = wid >> 1;         // 0..3 (M quarter, 32 rows)
    const int wc = wid & 1;          // 0..1 (N half, 64 cols)
    const int srow = tid >> 2;       // 0..127
    const int sk = (tid & 3) << 3;   // 0,8,16,24
    const int fr = lane & 15;
    const int kg = (lane >> 4) << 3; // 0,8,16,24

    f32x4 acc[2][4] = {};
    int4 ra, rb;

    auto load_tile = [&](int k0) {
        ra = *(const int4*)(A + (size_t)(row0 + srow) * K + k0 + sk);
        int c = col0 + srow;
        int4 b4 = {0, 0, 0, 0};
        if (c < Nc) b4 = *(const int4*)(B + (size_t)c * K + k0 + sk);
        rb = b4;
    };

    // prologue: stage tile 0, prefetch tile 1 to regs
    load_tile(0);
    *(int4*)(&As[0][srow][sk]) = ra;
    *(int4*)(&Bs[0][srow][sk]) = rb;
    const int T = K >> 5;
    if (T > 1) load_tile(32);
    __syncthreads();

    for (int t = 0; t < T; t++) {
        const int cur = t & 1;
        half8 a[2], b[4];
#pragma unroll
        for (int m = 0; m < 2; m++)
            a[m] = *(const half8*)&As[cur][wr * 32 + m * 16 + fr][kg];
#pragma unroll
        for (int n = 0; n < 4; n++)
            b[n] = *(const half8*)&Bs[cur][wc * 64 + n * 16 + fr][kg];
#pragma unroll
        for (int m = 0; m < 2; m++)
#pragma unroll
            for (int n = 0; n < 4; n++)
                acc[m][n] = __builtin_amdgcn_mfma_f32_16x16x32_f16(a[m], b[n], acc[m][n], 0, 0, 0);
        if (t + 1 < T) {
            *(int4*)(&As[cur ^ 1][srow][sk]) = ra;
            *(int4*)(&Bs[cur ^ 1][srow][sk]) = rb;
            if (t + 2 < T) load_tile((t + 2) << 5);
            __syncthreads();
        }
    }

    if (OM == 1) {
        // ---- LDS-transposed epilogue (coalesced __half stores) ----
        __syncthreads();                         // all waves done with As/Bs
        ushort* tile = &As[0][0][0] + wid * 1024; // 16x64 f16 per wave (8KB tot)
        const int hi = lane >> 4;
        const int rrow = lane >> 3;              // 0..7
        const int c8 = (lane & 7) * 8;           // 0..56
#pragma unroll
        for (int m = 0; m < 2; m++) {
#pragma unroll
            for (int n = 0; n < 4; n++)
#pragma unroll
                for (int rr4 = 0; rr4 < 4; rr4++)
                    tile[(hi * 4 + rr4) * 64 + n * 16 + fr] = f2h(acc[m][n][rr4]);
#pragma unroll
            for (int r2 = 0; r2 < 2; r2++) {
                int row = r2 * 8 + rrow;
                uint4 vv = *(uint4*)&tile[row * 64 + c8];
                int grow = row0 + wr * 32 + m * 16 + row;
                if (grow < M)
                    *(uint4*)((__half*)Cout + (size_t)grow * Nc + col0 + wc * 64 + c8) = vv;
            }
        }
    } else {
        // C/D layout: col = lane&15, row = (lane>>4)*4 + r
#pragma unroll
        for (int m = 0; m < 2; m++) {
            int rbase = row0 + wr * 32 + m * 16 + (lane >> 4) * 4;
#pragma unroll
            for (int n = 0; n < 4; n++) {
                int c = col0 + wc * 64 + n * 16 + fr;
                if (c < Nc) {
                    float bv = bias ? bias[c] : 0.f;
#pragma unroll
                    for (int rr4 = 0; rr4 < 4; rr4++) {
                        int rr = rbase + rr4;
                        if (rr < M)
                            ((float*)Cout)[(size_t)rr * Nc + c] = acc[m][n][rr4] + bv;
                    }
                }
            }
        }
    }
}

// ================= weight transpose to f16 =================
struct WDesc { const float* W; ushort* T; int K; int N; };
struct WPack { WDesc d[19]; };

__global__ void wconv_kernel(WPack p) {
    WDesc w = p.d[blockIdx.y];
    int idx = blockIdx.x * 256 + threadIdx.x;
    int total = w.K * w.N;
    if (idx >= total) return;
    int n = idx / w.K, k = idx - n * w.K;
    w.T[idx] = f2h(w.W[(size_t)k * w.N + n]);
}

// ================= fp32 -> f16 conversion =================
__global__ void conv_kernel(const float* __restrict__ in, ushort* __restrict__ o,
                            int total4) {
    int i = blockIdx.x * 256 + threadIdx.x;
    if (i >= total4) return;
    float4 v = *(const float4*)(in + (size_t)i * 4);
    ushort4 h;
    h.x = f2h(v.x); h.y = f2h(v.y); h.z = f2h(v.z); h.w = f2h(v.w);
    *(ushort4*)(o + (size_t)i * 4) = h;
}

// ================= CSR build =================
__global__ void hist_kernel(const int* __restrict__ dst, int* __restrict__ deg) {
    int e = blockIdx.x * blockDim.x + threadIdx.x;
    if (e >= EP) return;
    int d = (e < EE) ? dst[e] : (e - EE);
    atomicAdd(&deg[d], 1);
}

__global__ void bsum_kernel(const int* __restrict__ deg, int* __restrict__ bsum) {
    __shared__ int wsum[4];
    int i = blockIdx.x * 256 + threadIdx.x;
    int v = (i < NN) ? deg[i] : 0;
#pragma unroll
    for (int off = 32; off; off >>= 1) v += __shfl_xor(v, off);
    if ((threadIdx.x & 63) == 0) wsum[threadIdx.x >> 6] = v;
    __syncthreads();
    if (threadIdx.x == 0) bsum[blockIdx.x] = wsum[0] + wsum[1] + wsum[2] + wsum[3];
}

__global__ void bscan_kernel(const int* __restrict__ bsum, int* __restrict__ boff,
                             int* __restrict__ row_last, int nb) {
    int lane = threadIdx.x;  // 64 threads, 1 block
    int carry = 0;
    for (int base = 0; base < nb; base += 64) {
        int i = base + lane;
        int v = (i < nb) ? bsum[i] : 0;
        int x = v;
#pragma unroll
        for (int off = 1; off < 64; off <<= 1) {
            int y = __shfl_up(x, off);
            if (lane >= off) x += y;
        }
        if (i < nb) boff[i] = carry + x - v;
        carry += __shfl(x, 63);
    }
    if (lane == 0) *row_last = carry;
}

__global__ void blockscan_kernel(const int* __restrict__ deg, const int* __restrict__ boff,
                                 int* __restrict__ row_ptr, int* __restrict__ wptr) {
    __shared__ int wsum[4];
    int i = blockIdx.x * 256 + threadIdx.x;
    int v = (i < NN) ? deg[i] : 0;
    int lane = threadIdx.x & 63, w = threadIdx.x >> 6;
    int x = v;
#pragma unroll
    for (int off = 1; off < 64; off <<= 1) {
        int y = __shfl_up(x, off);
        if (lane >= off) x += y;
    }
    if (lane == 63) wsum[w] = x;
    __syncthreads();
    int wo = 0;
    for (int j = 0; j < w; j++) wo += wsum[j];
    if (i < NN) {
        int excl = boff[blockIdx.x] + wo + x - v;
        row_ptr[i] = excl;
        wptr[i] = excl;
    }
}

__global__ void scatter_kernel(const int* __restrict__ src, const int* __restrict__ dst,
                               int* __restrict__ wptr, int* __restrict__ col) {
    int e = blockIdx.x * blockDim.x + threadIdx.x;
    if (e >= EP) return;
    int s, d;
    if (e < EE) { s = src[e]; d = dst[e]; } else { s = d = e - EE; }
    int pos = atomicAdd(&wptr[d], 1);
    col[pos] = s;
}

// ================= fused GATv2 edge phase (R14/R17 exact, 68.0-68.4us) ====
// xlr f16: row = node, cols 0..255 = xl, 256..511 = xr.
// One wave per node as 4 groups of 16 lanes; 4 edges per iteration.
// Single-exp branch-free online softmax; lrelu via v_pk_max_f16;
// reduce-scatter group merge; distributed epilogue; 1-deep prefetch
// (2-deep measured WORSE in R18 — TLP already covers latency).
__global__ __launch_bounds__(256) void gat_fused(const __half* __restrict__ xlr,
                                                 const int* __restrict__ row_ptr,
                                                 const int* __restrict__ col,
                                                 const float* __restrict__ att,
                                                 const float* __restrict__ bias,
                                                 ushort* __restrict__ out) {
    int wid = blockIdx.x * 4 + (threadIdx.x >> 6);
    if (wid >= NN) return;
    const int lane = threadIdx.x & 63;
    const int g = lane >> 4, sl = lane & 15;
    const int start = row_ptr[wid], end = row_ptr[wid + 1];

    union U8 { uint4 q[2]; __half2 h[8]; unsigned u[8]; };

    // xr slice (this node), elems sl*16 .. sl*16+15
    U8 xr;
    {
        const uint4* xrp = (const uint4*)(xlr + (size_t)wid * XLR + 256 + sl * 16);
        xr.q[0] = xrp[0]; xr.q[1] = xrp[1];
    }
    // att slice as packed f16
    U8 at;
    {
        const float4* ap = (const float4*)(att + sl * 16);
        float4 a0 = ap[0], a1 = ap[1], a2_ = ap[2], a3 = ap[3];
        at.h[0] = __floats2half2_rn(a0.x, a0.y); at.h[1] = __floats2half2_rn(a0.z, a0.w);
        at.h[2] = __floats2half2_rn(a1.x, a1.y); at.h[3] = __floats2half2_rn(a1.z, a1.w);
        at.h[4] = __floats2half2_rn(a2_.x, a2_.y); at.h[5] = __floats2half2_rn(a2_.z, a2_.w);
        at.h[6] = __floats2half2_rn(a3.x, a3.y); at.h[7] = __floats2half2_rn(a3.z, a3.w);
    }
    const __half2 c02 = __floats2half2_rn(0.2f, 0.2f);

    float m = -1e30f, ssum = 0.f;
    __half2 a2[8];
#pragma unroll
    for (int j = 0; j < 8; j++) a2[j] = __floats2half2_rn(0.f, 0.f);

    // prologue: load first edge row for this group
    int eg = start + g;
    bool vc = eg < end;
    int sc = col[vc ? eg : (end - 1)];
    U8 xc;
    {
        const uint4* xp = (const uint4*)(xlr + (size_t)sc * XLR + sl * 16);
        xc.q[0] = xp[0]; xc.q[1] = xp[1];
    }

    for (int e0 = start; e0 < end; e0 += 4) {
        // ---- prefetch next iteration's row ----
        int egn = e0 + 4 + g;
        bool vn = egn < end;
        int sn = col[vn ? egn : (end - 1)];
        U8 xn;
        {
            const uint4* xp = (const uint4*)(xlr + (size_t)sn * XLR + sl * 16);
            xn.q[0] = xp[0]; xn.q[1] = xp[1];
        }

        // ---- score: dot(att, lrelu(xc + xr)), lrelu = max(x, 0.2x) ----
        float pf = 0.f;
#pragma unroll
        for (int i = 0; i < 8; i++) {
            union { __half2 h; unsigned u; } s2, s02, l2;
            s2.h = __hadd2(xc.h[i], xr.h[i]);
            s02.h = __hmul2(s2.h, c02);
            asm("v_pk_max_f16 %0, %1, %2" : "=v"(l2.u) : "v"(s2.u), "v"(s02.u));
            pf = __builtin_amdgcn_fdot2(l2.h, at.h[i], pf, false);
        }
#pragma unroll
        for (int off = 1; off < 16; off <<= 1) pf += __shfl_xor(pf, off);
        pf = vc ? pf : -INFINITY;

        // ---- branch-free online softmax, SINGLE exp ----
        float d = pf - m;
        float e1 = __expf(-fabsf(d));
        bool le = d <= 0.f;
        float f = le ? 1.f : e1;
        float w = le ? e1 : 1.f;
        ssum = fmaf(ssum, f, w);
        m = fmaxf(m, pf);
        __half2 f2 = __float2half2_rn(f);
        __half2 w2 = __float2half2_rn(w);
#pragma unroll
        for (int j = 0; j < 8; j++) a2[j] = __hfma2(a2[j], f2, __hmul2(xc.h[j], w2));

        xc = xn; vc = vn;
    }

    // ---- merge m/ssum across the 4 groups ----
    float m_all = m;
#pragma unroll
    for (int off = 16; off <= 32; off <<= 1) m_all = fmaxf(m_all, __shfl_xor(m_all, off));
    float fg = __expf(m - m_all);   // per-group rescale (0 for empty groups)
    ssum *= fg;
#pragma unroll
    for (int off = 16; off <= 32; off <<= 1) ssum += __shfl_xor(ssum, off);

    // ---- acc to f32, scale by fg ----
    float acc[16];
#pragma unroll
    for (int j = 0; j < 8; j++) {
        float2 fv = __half22float2(a2[j]);
        acc[2 * j] = fv.x * fg;
        acc[2 * j + 1] = fv.y * fg;
    }

    // ---- reduce-scatter across groups: lane ends with acc[4g + jj] summed ----
    const int gb1 = g >> 1, gb0 = g & 1;
    float t8[8];
#pragma unroll
    for (int jj = 0; jj < 8; jj++) {
        float keep = gb1 ? acc[8 + jj] : acc[jj];
        float send = gb1 ? acc[jj] : acc[8 + jj];
        t8[jj] = keep + __shfl_xor(send, 32);
    }
    float t4[4];
#pragma unroll
    for (int jj = 0; jj < 4; jj++) {
        float keep = gb0 ? t8[4 + jj] : t8[jj];
        float send = gb0 ? t8[jj] : t8[4 + jj];
        t4[jj] = keep + __shfl_xor(send, 16);
    }

    // ---- epilogue: lane (g,sl) handles elems sl*16 + 4g .. +3 ----
    float inv = 1.f / ssum;
    float4 b4 = *(const float4*)(bias + sl * 16 + 4 * g);
    const float* bf = (const float*)&b4;
    ushort4 hh;
    {
        ushort* hu = (ushort*)&hh;
#pragma unroll
        for (int jj = 0; jj < 4; jj++) {
            float o = gelu_exact(fmaf(t4[jj], inv, bf[jj]));
            hu[jj] = f2h(o);
        }
    }
    size_t ob = (size_t)wid * HH + sl * 16 + 4 * g;
    *(ushort4*)(out + ob) = hh;
}

// ================= mu/logstd/z + f16 of z =================
__global__ void z_kernel(const float* __restrict__ muls,
                         const float* __restrict__ mu_b, const float* __restrict__ ls_b,
                         const float* __restrict__ eps,
                         float* __restrict__ mu, float* __restrict__ lstd,
                         float* __restrict__ z, ushort* __restrict__ zf) {
    int i = blockIdx.x * 256 + threadIdx.x;
    if (i >= NN * LL) return;
    int row = i >> 6, j = i & 63;
    float mv = muls[(size_t)row * 128 + j] + mu_b[j];
    float lv = fminf(muls[(size_t)row * 128 + 64 + j] + ls_b[j], 10.f);
    float zv = fmaf(eps[i], __expf(lv), mv);
    mu[i] = mv;
    lstd[i] = lv;
    z[i] = zv;
    zf[i] = f2h(zv);
}

extern "C" void kernel_launch(void* const* d_in, const int* in_sizes, int n_in,
                              void* d_out, int out_size, void* d_ws, size_t ws_size,
                              hipStream_t stream) {
    const float* x       = (const float*)d_in[0];
    const int*   ei      = (const int*)d_in[1];
    const float* eps     = (const float*)d_in[2];
    const float* enc_Wl  = (const float*)d_in[3];
    const float* enc_Wr  = (const float*)d_in[4];
    const float* enc_att = (const float*)d_in[5];
    const float* enc_b   = (const float*)d_in[6];
    const float* mu_W    = (const float*)d_in[7];
    const float* mu_b    = (const float*)d_in[8];
    const float* ls_W    = (const float*)d_in[9];
    const float* ls_b    = (const float*)d_in[10];
    const float* dec0_Wl = (const float*)d_in[11];
    const float* dec0_Wr = (const float*)d_in[12];
    const float* dec0_att= (const float*)d_in[13];
    const float* dec0_b  = (const float*)d_in[14];
    const float* dec_Wl  = (const float*)d_in[15];
    const float* dec_Wr  = (const float*)d_in[16];
    const float* dec_att = (const float*)d_in[17];
    const float* dec_b   = (const float*)d_in[18];
    const float* out_W   = (const float*)d_in[19];
    const float* out_b   = (const float*)d_in[20];

    const int* esrc = ei;
    const int* edst = ei + EE;

    float* out_f = (float*)d_out;
    float* xrec = out_f;
    float* z    = out_f + (size_t)NN * DD;
    float* mu   = z + (size_t)NN * LL;
    float* lstd = mu + (size_t)NN * LL;

    // ---- workspace layout ----
    float* wsf = (float*)d_ws;
    __half* xlr = (__half*)wsf;                     // MP*512 f16  (= MP*256 floats)
    float* muls = wsf + (size_t)MP * 256;           // MP*128 f32
    ushort* Af = (ushort*)(muls + (size_t)MP * 128);// MP*256 f16 (GEMM A / gat out)
    ushort* Th = Af + (size_t)MP * 256;             // 1,048,576 f16
    int* deg     = (int*)(Th + 1048576);
    int* row_ptr = deg + NN;
    int* wptr    = row_ptr + NN + 1;
    int* col     = wptr + NN;
    int* bsum    = col + EP;
    int* boff    = bsum + 256;

    // weight pack: per-layer Wl/Wr pairs CONTIGUOUS so fused Nc=512 GEMM works
    WPack p;
    size_t off = 0;
    int wi = 0;
    auto add = [&](const float* W, int K, int N) {
        p.d[wi] = {W, Th + off, K, N};
        off += (size_t)K * N;
        wi++;
    };
    for (int l = 0; l < 4; l++) {                     // 0..7: enc (Wl,Wr)*4
        add(enc_Wl + (size_t)l * DD * HH, DD, HH);
        add(enc_Wr + (size_t)l * DD * HH, DD, HH);
    }
    add(dec0_Wl, LL, HH);                             // 8,9
    add(dec0_Wr, LL, HH);
    for (int l = 0; l < 3; l++) {                     // 10..15: dec (Wl,Wr)*3
        add(dec_Wl + (size_t)l * HH * HH, HH, HH);
        add(dec_Wr + (size_t)l * HH * HH, HH, HH);
    }
    add(out_W, HH, DD);                               // 16
    add(mu_W, HH, LL);                                // 17,18 contiguous -> Nc=128
    add(ls_W, HH, LL);

    const int eb = (EP + 255) / 256;
    const int nb = (NN + 3) / 4;            // gat: 4 nodes (waves) per block
    const int cb = (NN * 64 + 255) / 256;
    const int NBY = MP / 128;               // 391
    const int g_pair = 4 * NBY;             // Nc=512 fused Wl|Wr
    const int g_out  = 2 * NBY;             // Nc=256
    const int g_muls = 1 * NBY;             // Nc=128 fused mu|ls

    // ---- weight conversion + CSR build ----
    wconv_kernel<<<dim3(256, 19), 256, 0, stream>>>(p);
    (void)hipMemsetAsync(deg, 0, (size_t)NN * sizeof(int), stream);
    hist_kernel<<<eb, 256, 0, stream>>>(edst, deg);
    bsum_kernel<<<NB2, 256, 0, stream>>>(deg, bsum);
    bscan_kernel<<<1, 64, 0, stream>>>(bsum, boff, row_ptr + NN, NB2);
    blockscan_kernel<<<NB2, 256, 0, stream>>>(deg, boff, row_ptr, wptr);
    scatter_kernel<<<eb, 256, 0, stream>>>(esrc, edst, wptr, col);

    // ---- x -> f16 ----
    conv_kernel<<<cb, 256, 0, stream>>>(x, Af, NN * 64);

    // ---- encoder ----
    for (int l = 0; l < 4; l++) {
        mm_f16<1><<<g_pair, 512, 0, stream>>>(Af, p.d[2 * l].T, nullptr,
                                              xlr, NN, DD, XLR, 4);
        gat_fused<<<nb, 256, 0, stream>>>(xlr, row_ptr, col,
                                          enc_att + (size_t)l * HH,
                                          enc_b + (size_t)l * HH, Af);
    }

    // ---- mu / logstd / z (fused Nc=128 GEMM) ----
    mm_f16<0><<<g_muls, 512, 0, stream>>>(Af, p.d[17].T, nullptr,
                                          muls, NN, HH, 128, 1);
    z_kernel<<<(NN * LL + 255) / 256, 256, 0, stream>>>(muls, mu_b, ls_b, eps,
                                                        mu, lstd, z, Af);

    // ---- decoder ----
    for (int l = 0; l < 4; l++) {
        const ushort* BT;
        const float *at, *bb;
        int K;
        if (l == 0) {
            BT = p.d[8].T;                   // dec0 Wl|Wr combined [512][64]
            at = dec0_att; bb = dec0_b; K = LL;
        } else {
            BT = p.d[10 + 2 * (l - 1)].T;
            at = dec_att + (size_t)(l - 1) * HH;
            bb = dec_b + (size_t)(l - 1) * HH;
            K = HH;
        }
        mm_f16<1><<<g_pair, 512, 0, stream>>>(Af, BT, nullptr, xlr, NN, K, XLR, 4);
        gat_fused<<<nb, 256, 0, stream>>>(xlr, row_ptr, col, at, bb, Af);
    }

    // ---- output projection ----
    mm_f16<0><<<g_out, 512, 0, stream>>>(Af, p.d[16].T, out_b, xrec, NN, HH, DD, 2);
}